// Round 3
// baseline (115.809 us; speedup 1.0000x reference)
//
#include <hip/hip_runtime.h>
#include <math.h>

#define CC    144
#define WW    9225
#define KWW   10
#define FF    64
#define H1N   128
#define CONVN (WW - KWW + 1)   // 9216
#define CFN   (CC * FF)        // 9216
#define CATN  (CFN + CONVN)    // 18432
#define WP    9232             // padded xcopy row stride (mult of 4; 36928 B, 16B-aligned)
#define NCPY4 (4 * CC * (WP / 4))

typedef float f32x4 __attribute__((ext_vector_type(4)));

// ---------------------------------------------------------------------------
// Pre-kernel: 4 shift-aligned copies of x. xcopy[(s*CC+c)*WP + j] = x[c, s+j]
// (zero-padded past W). Makes every fc row's x-side readable as aligned float4.
// ---------------------------------------------------------------------------
__global__ __launch_bounds__(256) void k_mkcopies(
    const float* __restrict__ x, float* __restrict__ xcopy)
{
    const int total = NCPY4;
    for (int idx = blockIdx.x * 256 + threadIdx.x; idx < total;
         idx += gridDim.x * 256) {
        const int q  = idx % (WP / 4);
        const int sc = idx / (WP / 4);    // s*CC + c
        const int c  = sc % CC;
        const int s  = sc / CC;
        const int j0 = q * 4;
        const float* __restrict__ xr = x + (size_t)c * WW;
        float4 v;
        v.x = (s + j0 + 0 < WW) ? xr[s + j0 + 0] : 0.f;
        v.y = (s + j0 + 1 < WW) ? xr[s + j0 + 1] : 0.f;
        v.z = (s + j0 + 2 < WW) ? xr[s + j0 + 2] : 0.f;
        v.w = (s + j0 + 3 < WW) ? xr[s + j0 + 3] : 0.f;
        ((float4*)(xcopy + (size_t)sc * WP))[q] = v;
    }
}

// ---------------------------------------------------------------------------
// Stage 1 v2: blocks [0,CFN) fc rows (x via aligned copy), [CFN,+36) conv.
// ---------------------------------------------------------------------------
__global__ __launch_bounds__(256) void k_front_v2(
    const float* __restrict__ x,
    const float* __restrict__ Wfc,
    const float* __restrict__ bfc,
    const float* __restrict__ Kc,
    const float* __restrict__ bconv,
    const float* __restrict__ xcopy,
    float* __restrict__ concat)
{
    __shared__ float sm[CC * KWW];
    const int b   = blockIdx.x;
    const int tid = threadIdx.x;

    if (b < CFN) {
        const int c = b >> 6;
        const size_t base = (size_t)b * WW;
        const float* __restrict__ wr = Wfc + base;
        const float* __restrict__ xr = x + (size_t)c * WW;
        const int pro = (int)((4u - ((unsigned)(base & 3u))) & 3u);

        float acc = 0.f;
        if (tid < pro) acc += wr[tid] * xr[tid];

        const int rem  = WW - pro;
        const int nv   = rem >> 2;
        const int tail = rem & 3;
        const f32x4* __restrict__ wv = (const f32x4*)(wr + pro);
        const f32x4* __restrict__ xv =
            (const f32x4*)(xcopy + (size_t)(pro * CC + c) * WP);

        for (int i = tid; i < nv; i += 256) {
            const f32x4 wq = __builtin_nontemporal_load(wv + i);
            const f32x4 xq = xv[i];
            acc += wq.x * xq.x + wq.y * xq.y + wq.z * xq.z + wq.w * xq.w;
        }
        if (tid < tail) {
            const int w0 = pro + (nv << 2) + tid;
            acc += wr[w0] * xr[w0];
        }

        #pragma unroll
        for (int off = 32; off > 0; off >>= 1)
            acc += __shfl_xor(acc, off, 64);
        const int lane = tid & 63, wid = tid >> 6;
        if (lane == 0) sm[wid] = acc;
        __syncthreads();
        if (tid == 0)
            concat[b] = sm[0] + sm[1] + sm[2] + sm[3] + bfc[b];
    } else {
        for (int i = tid; i < CC * KWW; i += 256) sm[i] = Kc[i];
        __syncthreads();
        const int p = (b - CFN) * 256 + tid;
        float acc = bconv[0];
        for (int c = 0; c < CC; ++c) {
            const float* __restrict__ xr = x + (size_t)c * WW + p;
            const float* __restrict__ kr = sm + c * KWW;
            #pragma unroll
            for (int k = 0; k < KWW; ++k)
                acc = fmaf(xr[k], kr[k], acc);
        }
        concat[CFN + p] = acc;
    }
}

// ---------------------------------------------------------------------------
// Stage 2 v2: 256 blocks; block j = (h = j>>1, half = j&1) does a half-row
// partial dot (no bias/relu) -> partial[j].
// ---------------------------------------------------------------------------
__global__ __launch_bounds__(256) void k_layer1_v2(
    const float* __restrict__ W1,
    const float* __restrict__ concat,
    float* __restrict__ partial)
{
    __shared__ float sm[4];
    const int j = blockIdx.x, tid = threadIdx.x;
    const int h = j >> 1, half = j & 1;
    const f32x4* __restrict__ wr =
        (const f32x4*)(W1 + (size_t)h * CATN + half * (CATN / 2));
    const f32x4* __restrict__ cv =
        (const f32x4*)(concat + half * (CATN / 2));

    float acc = 0.f;
    for (int i = tid; i < CATN / 8; i += 256) {   // 2304 -> 9 iters
        const f32x4 a = __builtin_nontemporal_load(wr + i);
        const f32x4 q = cv[i];
        acc += a.x * q.x + a.y * q.y + a.z * q.z + a.w * q.w;
    }
    #pragma unroll
    for (int off = 32; off > 0; off >>= 1)
        acc += __shfl_xor(acc, off, 64);
    if ((tid & 63) == 0) sm[tid >> 6] = acc;
    __syncthreads();
    if (tid == 0)
        partial[j] = sm[0] + sm[1] + sm[2] + sm[3];
}

// ---------------------------------------------------------------------------
// Stage 3 v2: combine partials + bias + relu, dot with W2, relu, sigmoid.
// ---------------------------------------------------------------------------
__global__ __launch_bounds__(128) void k_final_v2(
    const float* __restrict__ partial, // [256]
    const float* __restrict__ b1,      // [H1]
    const float* __restrict__ W2,      // [1, H1]
    const float* __restrict__ b2,      // [1]
    float* __restrict__ out)           // [1]
{
    __shared__ float sm[2];
    const int tid = threadIdx.x;
    float v = fmaxf(partial[2 * tid] + partial[2 * tid + 1] + b1[tid], 0.f)
              * W2[tid];
    #pragma unroll
    for (int off = 32; off > 0; off >>= 1)
        v += __shfl_xor(v, off, 64);
    if ((tid & 63) == 0) sm[tid >> 6] = v;
    __syncthreads();
    if (tid == 0) {
        float z = sm[0] + sm[1] + b2[0];
        z = fmaxf(z, 0.f);
        out[0] = 1.f / (1.f + expf(-z));
    }
}

// ============================ fallback (round-2) ============================
__global__ __launch_bounds__(256) void k_front_v1(
    const float* __restrict__ x, const float* __restrict__ Wfc,
    const float* __restrict__ bfc, const float* __restrict__ Kc,
    const float* __restrict__ bconv, float* __restrict__ concat)
{
    __shared__ float sm[CC * KWW];
    const int b = blockIdx.x, tid = threadIdx.x;
    if (b < CFN) {
        const int c = b >> 6;
        const size_t base = (size_t)b * WW;
        const float* __restrict__ xr = x + (size_t)c * WW;
        const float* __restrict__ wr = Wfc + base;
        const int pro = (int)((4u - ((unsigned)(base & 3u))) & 3u);
        float acc = 0.f;
        if (tid < pro) acc += wr[tid] * xr[tid];
        const int rem = WW - pro, nv = rem >> 2, tail = rem & 3;
        const float4* __restrict__ wv = (const float4*)(wr + pro);
        for (int i = tid; i < nv; i += 256) {
            const float4 wq = wv[i];
            const int w0 = pro + (i << 2);
            acc += wq.x * xr[w0] + wq.y * xr[w0 + 1]
                 + wq.z * xr[w0 + 2] + wq.w * xr[w0 + 3];
        }
        if (tid < tail) {
            const int w0 = pro + (nv << 2) + tid;
            acc += wr[w0] * xr[w0];
        }
        #pragma unroll
        for (int off = 32; off > 0; off >>= 1)
            acc += __shfl_xor(acc, off, 64);
        if ((tid & 63) == 0) sm[tid >> 6] = acc;
        __syncthreads();
        if (tid == 0) concat[b] = sm[0] + sm[1] + sm[2] + sm[3] + bfc[b];
    } else {
        for (int i = tid; i < CC * KWW; i += 256) sm[i] = Kc[i];
        __syncthreads();
        const int p = (b - CFN) * 256 + tid;
        float acc = bconv[0];
        for (int c = 0; c < CC; ++c) {
            const float* __restrict__ xr = x + (size_t)c * WW + p;
            const float* __restrict__ kr = sm + c * KWW;
            #pragma unroll
            for (int k = 0; k < KWW; ++k) acc = fmaf(xr[k], kr[k], acc);
        }
        concat[CFN + p] = acc;
    }
}

__global__ __launch_bounds__(256) void k_layer1_v1(
    const float* __restrict__ W1, const float* __restrict__ b1,
    const float* __restrict__ concat, float* __restrict__ second)
{
    __shared__ float sm[4];
    const int h = blockIdx.x, tid = threadIdx.x;
    const float4* __restrict__ wr = (const float4*)(W1 + (size_t)h * CATN);
    const float4* __restrict__ cv = (const float4*)concat;
    float acc = 0.f;
    for (int i = tid; i < CATN / 4; i += 256) {
        const float4 a = wr[i], q = cv[i];
        acc += a.x * q.x + a.y * q.y + a.z * q.z + a.w * q.w;
    }
    #pragma unroll
    for (int off = 32; off > 0; off >>= 1)
        acc += __shfl_xor(acc, off, 64);
    if ((tid & 63) == 0) sm[tid >> 6] = acc;
    __syncthreads();
    if (tid == 0)
        second[h] = fmaxf(sm[0] + sm[1] + sm[2] + sm[3] + b1[h], 0.f);
}

__global__ __launch_bounds__(128) void k_final_v1(
    const float* __restrict__ second, const float* __restrict__ W2,
    const float* __restrict__ b2, float* __restrict__ out)
{
    __shared__ float sm[2];
    const int tid = threadIdx.x;
    float v = second[tid] * W2[tid];
    #pragma unroll
    for (int off = 32; off > 0; off >>= 1)
        v += __shfl_xor(v, off, 64);
    if ((tid & 63) == 0) sm[tid >> 6] = v;
    __syncthreads();
    if (tid == 0) {
        float z = fmaxf(sm[0] + sm[1] + b2[0], 0.f);
        out[0] = 1.f / (1.f + expf(-z));
    }
}

extern "C" void kernel_launch(void* const* d_in, const int* in_sizes, int n_in,
                              void* d_out, int out_size, void* d_ws, size_t ws_size,
                              hipStream_t stream) {
    const float* x     = (const float*)d_in[0];
    const float* Wfc   = (const float*)d_in[1];
    const float* bfc   = (const float*)d_in[2];
    const float* Kc    = (const float*)d_in[3];
    const float* bconv = (const float*)d_in[4];
    const float* W1    = (const float*)d_in[5];
    const float* b1    = (const float*)d_in[6];
    const float* W2    = (const float*)d_in[7];
    const float* b2    = (const float*)d_in[8];
    float* out = (float*)d_out;

    float* concat = (float*)d_ws;                       // [CATN]
    const size_t need =
        ((size_t)(CATN + 256) + (size_t)4 * CC * WP) * sizeof(float);

    if (ws_size >= need) {
        float* partial = concat + CATN;                 // [256]
        float* xcopy   = concat + CATN + 256;           // 16B-aligned offset
        k_mkcopies <<<1024, 256, 0, stream>>>(x, xcopy);
        k_front_v2 <<<CFN + (CONVN / 256), 256, 0, stream>>>(
            x, Wfc, bfc, Kc, bconv, xcopy, concat);
        k_layer1_v2<<<256, 256, 0, stream>>>(W1, concat, partial);
        k_final_v2 <<<1, 128, 0, stream>>>(partial, b1, W2, b2, out);
    } else {
        float* second = concat + CATN;                  // [H1]
        k_front_v1 <<<CFN + (CONVN / 256), 256, 0, stream>>>(
            x, Wfc, bfc, Kc, bconv, concat);
        k_layer1_v1<<<H1N, 256, 0, stream>>>(W1, b1, concat, second);
        k_final_v1 <<<1, 128, 0, stream>>>(second, W2, b2, out);
    }
}

// Round 4
// 88.112 us; speedup vs baseline: 1.3143x; 1.3143x over previous
//
#include <hip/hip_runtime.h>
#include <math.h>

#define CC    144
#define WW    9225
#define KWW   10
#define FF    64
#define H1N   128
#define CONVN (WW - KWW + 1)   // 9216
#define CFN   (CC * FF)        // 9216
#define CATN  (CFN + CONVN)    // 18432
#define FCB   (CFN / 4)        // 2304 fc blocks (4 waves each, 1 row/wave)

typedef float f32x4 __attribute__((ext_vector_type(4)));

// ---------------------------------------------------------------------------
// Stage 1 v3: blocks [0,FCB): 4 waves, one fc row per wave, barrier-free.
//             blocks [FCB, FCB+36): conv (256 positions/block).
// ---------------------------------------------------------------------------
__global__ __launch_bounds__(256) void k_front_v3(
    const float* __restrict__ x,     // [C, W]
    const float* __restrict__ Wfc,   // [C, F, W]
    const float* __restrict__ bfc,   // [C, F]
    const float* __restrict__ Kc,    // [C, KW]
    const float* __restrict__ bconv, // [1]
    float* __restrict__ concat)      // [CATN]
{
    __shared__ float sm[CC * KWW];   // used by conv blocks only
    const int bid = blockIdx.x;
    const int tid = threadIdx.x;

    if (bid < FCB) {
        // ---- one row per wave: r = bid*4 + wave
        const int wave = tid >> 6;
        const int lane = tid & 63;
        const int r    = bid * 4 + wave;          // fc row index [0, CFN)
        const int c    = r >> 6;                  // channel
        const size_t base = (size_t)r * WW;
        const float* __restrict__ wr = Wfc + base;
        const float* __restrict__ xr = x + (size_t)c * WW;

        // alignment prologue for W's float4 stream (W=9225 odd)
        const int pro = (int)((4u - ((unsigned)(base & 3u))) & 3u);
        float acc = 0.f;
        if (lane < pro) acc += wr[lane] * xr[lane];

        const int rem  = WW - pro;
        const int nv   = rem >> 2;                // 2305 or 2306 float4s
        const int tail = rem & 3;
        const f32x4* __restrict__ wv = (const f32x4*)(wr + pro);

        #pragma unroll 4
        for (int i = lane; i < nv; i += 64) {     // ~36 iters/lane
            const f32x4 wq = wv[i];
            const int w0 = pro + (i << 2);
            acc += wq.x * xr[w0]     + wq.y * xr[w0 + 1]
                 + wq.z * xr[w0 + 2] + wq.w * xr[w0 + 3];
        }
        if (lane < tail) {
            const int w0 = pro + (nv << 2) + lane;
            acc += wr[w0] * xr[w0];
        }

        // wave-only reduction — no LDS, no __syncthreads
        #pragma unroll
        for (int off = 32; off > 0; off >>= 1)
            acc += __shfl_xor(acc, off, 64);
        if (lane == 0)
            concat[r] = acc + bfc[r];
    } else {
        // ---- conv: position p = (bid-FCB)*256 + tid
        for (int i = tid; i < CC * KWW; i += 256) sm[i] = Kc[i];
        __syncthreads();

        const int p = (bid - FCB) * 256 + tid;    // 36*256 == 9216 exactly
        float acc = bconv[0];
        for (int c = 0; c < CC; ++c) {
            const float* __restrict__ xr = x + (size_t)c * WW + p;
            const float* __restrict__ kr = sm + c * KWW;
            #pragma unroll
            for (int k = 0; k < KWW; ++k)
                acc = fmaf(xr[k], kr[k], acc);
        }
        concat[CFN + p] = acc;
    }
}

// ---------------------------------------------------------------------------
// Stage 2: 256 blocks; block j = (h = j>>1, half = j&1) half-row partial dot.
// ---------------------------------------------------------------------------
__global__ __launch_bounds__(256) void k_layer1_v2(
    const float* __restrict__ W1,     // [H1, CAT]
    const float* __restrict__ concat, // [CAT]
    float* __restrict__ partial)      // [256]
{
    __shared__ float sm[4];
    const int j = blockIdx.x, tid = threadIdx.x;
    const int h = j >> 1, half = j & 1;
    const f32x4* __restrict__ wr =
        (const f32x4*)(W1 + (size_t)h * CATN + half * (CATN / 2));
    const f32x4* __restrict__ cv =
        (const f32x4*)(concat + half * (CATN / 2));

    float acc = 0.f;
    for (int i = tid; i < CATN / 8; i += 256) {   // 9 iters
        const f32x4 a = wr[i];
        const f32x4 q = cv[i];
        acc += a.x * q.x + a.y * q.y + a.z * q.z + a.w * q.w;
    }
    #pragma unroll
    for (int off = 32; off > 0; off >>= 1)
        acc += __shfl_xor(acc, off, 64);
    if ((tid & 63) == 0) sm[tid >> 6] = acc;
    __syncthreads();
    if (tid == 0)
        partial[j] = sm[0] + sm[1] + sm[2] + sm[3];
}

// ---------------------------------------------------------------------------
// Stage 3: combine partials + bias + relu, dot with W2, relu, sigmoid.
// ---------------------------------------------------------------------------
__global__ __launch_bounds__(128) void k_final_v2(
    const float* __restrict__ partial, // [256]
    const float* __restrict__ b1,      // [H1]
    const float* __restrict__ W2,      // [1, H1]
    const float* __restrict__ b2,      // [1]
    float* __restrict__ out)           // [1]
{
    __shared__ float sm[2];
    const int tid = threadIdx.x;
    float v = fmaxf(partial[2 * tid] + partial[2 * tid + 1] + b1[tid], 0.f)
              * W2[tid];
    #pragma unroll
    for (int off = 32; off > 0; off >>= 1)
        v += __shfl_xor(v, off, 64);
    if ((tid & 63) == 0) sm[tid >> 6] = v;
    __syncthreads();
    if (tid == 0) {
        float z = sm[0] + sm[1] + b2[0];
        z = fmaxf(z, 0.f);
        out[0] = 1.f / (1.f + expf(-z));
    }
}

extern "C" void kernel_launch(void* const* d_in, const int* in_sizes, int n_in,
                              void* d_out, int out_size, void* d_ws, size_t ws_size,
                              hipStream_t stream) {
    const float* x     = (const float*)d_in[0];
    const float* Wfc   = (const float*)d_in[1];
    const float* bfc   = (const float*)d_in[2];
    const float* Kc    = (const float*)d_in[3];
    const float* bconv = (const float*)d_in[4];
    const float* W1    = (const float*)d_in[5];
    const float* b1    = (const float*)d_in[6];
    const float* W2    = (const float*)d_in[7];
    const float* b2    = (const float*)d_in[8];
    float* out = (float*)d_out;

    float* concat  = (float*)d_ws;         // [CATN]
    float* partial = concat + CATN;        // [256]

    k_front_v3 <<<FCB + (CONVN / 256), 256, 0, stream>>>(
        x, Wfc, bfc, Kc, bconv, concat);
    k_layer1_v2<<<256, 256, 0, stream>>>(W1, concat, partial);
    k_final_v2 <<<1, 128, 0, stream>>>(partial, b1, W2, b2, out);
}